// Round 1
// baseline (443.627 us; speedup 1.0000x reference)
//
#include <hip/hip_runtime.h>

// Causal depthwise conv1d, NHC layout, fp32.
// out[b,t,c] = bias[c] + sum_{k=0..K-1} w[k,0,c] * x[b, t-(K-1)+k, c]
// B=4, T=8192, C=2048, K=4.
//
// Memory-bound design: one thread per (b, t-chunk, float4-channel-group).
// Sliding register window of K-1 previous x rows -> each x element read once
// (plus K-1 halo rows per 64-row chunk, ~4.7% extra fetch).
// Consecutive threads = consecutive c4 -> fully coalesced 16B/lane loads/stores.

constexpr int B = 4;
constexpr int T = 8192;
constexpr int C = 2048;
constexpr int C4 = C / 4;        // 512 float4 groups per row
constexpr int TCHUNK = 64;       // rows per thread
constexpr int NCHUNK = T / TCHUNK; // 128

__global__ __launch_bounds__(256) void causal_conv1d_kernel(
    const float4* __restrict__ x,     // [B*T*C4]
    const float*  __restrict__ w,     // [K, 1, C] flat: k*C + c
    const float*  __restrict__ bias,  // [C]
    float4* __restrict__ out)         // [B*T*C4]
{
    const int idx = blockIdx.x * blockDim.x + threadIdx.x;
    const int c4   = idx & (C4 - 1);          // fastest-varying -> coalesced
    const int rest = idx >> 9;                // / 512
    const int tc   = rest & (NCHUNK - 1);
    const int b    = rest >> 7;               // / 128
    const int t0   = tc * TCHUNK;

    // Per-channel weights (K=4) and bias, vectorized.
    const float4* w4 = (const float4*)w;
    const float4 w0 = w4[0 * C4 + c4];
    const float4 w1 = w4[1 * C4 + c4];
    const float4 w2 = w4[2 * C4 + c4];
    const float4 w3 = w4[3 * C4 + c4];
    const float4 bs = ((const float4*)bias)[c4];

    const float4* xb = x   + (size_t)b * T * C4;
    float4*       ob = out + (size_t)b * T * C4;

    const float4 zero = make_float4(0.f, 0.f, 0.f, 0.f);
    // Sliding window: xm1 = x[t-1], xm2 = x[t-2], xm3 = x[t-3].
    // t0 is a multiple of TCHUNK, so only t0==0 needs the zero padding.
    float4 xm3 = (t0 >= 3) ? xb[(size_t)(t0 - 3) * C4 + c4] : zero;
    float4 xm2 = (t0 >= 2) ? xb[(size_t)(t0 - 2) * C4 + c4] : zero;
    float4 xm1 = (t0 >= 1) ? xb[(size_t)(t0 - 1) * C4 + c4] : zero;

#pragma unroll 4
    for (int t = t0; t < t0 + TCHUNK; ++t) {
        const float4 xt = xb[(size_t)t * C4 + c4];
        float4 o;
        o.x = fmaf(w3.x, xt.x, fmaf(w2.x, xm1.x, fmaf(w1.x, xm2.x, fmaf(w0.x, xm3.x, bs.x))));
        o.y = fmaf(w3.y, xt.y, fmaf(w2.y, xm1.y, fmaf(w1.y, xm2.y, fmaf(w0.y, xm3.y, bs.y))));
        o.z = fmaf(w3.z, xt.z, fmaf(w2.z, xm1.z, fmaf(w1.z, xm2.z, fmaf(w0.z, xm3.z, bs.z))));
        o.w = fmaf(w3.w, xt.w, fmaf(w2.w, xm1.w, fmaf(w1.w, xm2.w, fmaf(w0.w, xm3.w, bs.w))));
        ob[(size_t)t * C4 + c4] = o;
        xm3 = xm2;
        xm2 = xm1;
        xm1 = xt;
    }
}

extern "C" void kernel_launch(void* const* d_in, const int* in_sizes, int n_in,
                              void* d_out, int out_size, void* d_ws, size_t ws_size,
                              hipStream_t stream) {
    const float4* x    = (const float4*)d_in[0];
    const float*  w    = (const float*)d_in[1];
    const float*  bias = (const float*)d_in[2];
    float4* out = (float4*)d_out;

    const int total_threads = B * NCHUNK * C4;   // 4*128*512 = 262144
    const int block = 256;
    const int grid = total_threads / block;      // 1024
    causal_conv1d_kernel<<<grid, block, 0, stream>>>(x, w, bias, out);
}

// Round 2
// 437.847 us; speedup vs baseline: 1.0132x; 1.0132x over previous
//
#include <hip/hip_runtime.h>

// Causal depthwise conv1d, NHC layout, fp32.
// out[b,t,c] = bias[c] + sum_{k=0..3} w[k,0,c] * x[b, t-3+k, c]
// B=4, T=8192, C=2048, K=4.
//
// Copy-kernel shape for max memory-level parallelism: each thread produces
// TCHUNK=8 consecutive t-outputs for one float4 channel group. All 11 x-loads
// (t0-3 .. t0+7) are independent and issued before any FMA -> ~11 KB in
// flight per wave, no loop-carried dependency (round-1's sliding window
// serialized on vmcnt and ran 5x off roofline).
// Consecutive threads = consecutive c4 -> fully coalesced 16 B/lane.

constexpr int B = 4;
constexpr int T = 8192;
constexpr int C = 2048;
constexpr int C4 = C / 4;            // 512 float4 groups per row
constexpr int TCHUNK = 8;            // outputs per thread
constexpr int NCHUNK = T / TCHUNK;   // 1024
constexpr int NLOAD = TCHUNK + 3;    // 11 x rows per thread

__global__ __launch_bounds__(256) void causal_conv1d_kernel(
    const float4* __restrict__ x,     // [B*T*C4]
    const float*  __restrict__ w,     // [K,1,C] flat: k*C + c
    const float*  __restrict__ bias,  // [C]
    float4* __restrict__ out)         // [B*T*C4]
{
    const int idx  = blockIdx.x * blockDim.x + threadIdx.x;
    const int c4   = idx & (C4 - 1);          // fastest-varying -> coalesced
    const int rest = idx >> 9;                // / 512 ; block-uniform
    const int tc   = rest & (NCHUNK - 1);
    const int b    = rest >> 10;              // / 1024
    const int t0   = tc * TCHUNK;

    const float4* xb = x   + (size_t)b * T * C4;
    float4*       ob = out + (size_t)b * T * C4;

    const float4 zero = make_float4(0.f, 0.f, 0.f, 0.f);
    float4 xv[NLOAD];

    // t0 is block-uniform -> no divergence. Issue every load up front.
    if (t0 != 0) {
#pragma unroll
        for (int i = 0; i < NLOAD; ++i)
            xv[i] = xb[(size_t)(t0 - 3 + i) * C4 + c4];
    } else {
        xv[0] = zero; xv[1] = zero; xv[2] = zero;
#pragma unroll
        for (int i = 3; i < NLOAD; ++i)
            xv[i] = xb[(size_t)(t0 - 3 + i) * C4 + c4];
    }

    // Per-channel weights (K=4) and bias, vectorized (33 KB total: L2-resident).
    const float4* w4 = (const float4*)w;
    const float4 w0 = w4[0 * C4 + c4];
    const float4 w1 = w4[1 * C4 + c4];
    const float4 w2 = w4[2 * C4 + c4];
    const float4 w3 = w4[3 * C4 + c4];
    const float4 bs = ((const float4*)bias)[c4];

#pragma unroll
    for (int j = 0; j < TCHUNK; ++j) {
        const float4 a0 = xv[j], a1 = xv[j + 1], a2 = xv[j + 2], a3 = xv[j + 3];
        float4 o;
        o.x = fmaf(w3.x, a3.x, fmaf(w2.x, a2.x, fmaf(w1.x, a1.x, fmaf(w0.x, a0.x, bs.x))));
        o.y = fmaf(w3.y, a3.y, fmaf(w2.y, a2.y, fmaf(w1.y, a1.y, fmaf(w0.y, a0.y, bs.y))));
        o.z = fmaf(w3.z, a3.z, fmaf(w2.z, a2.z, fmaf(w1.z, a1.z, fmaf(w0.z, a0.z, bs.z))));
        o.w = fmaf(w3.w, a3.w, fmaf(w2.w, a2.w, fmaf(w1.w, a1.w, fmaf(w0.w, a0.w, bs.w))));
        ob[(size_t)(t0 + j) * C4 + c4] = o;
    }
}

extern "C" void kernel_launch(void* const* d_in, const int* in_sizes, int n_in,
                              void* d_out, int out_size, void* d_ws, size_t ws_size,
                              hipStream_t stream) {
    const float4* x    = (const float4*)d_in[0];
    const float*  w    = (const float*)d_in[1];
    const float*  bias = (const float*)d_in[2];
    float4* out = (float4*)d_out;

    const int total_threads = B * NCHUNK * C4;   // 4*1024*512 = 2,097,152
    const int block = 256;
    const int grid = total_threads / block;      // 8192
    causal_conv1d_kernel<<<grid, block, 0, stream>>>(x, w, bias, out);
}